// Round 7
// baseline (368.473 us; speedup 1.0000x reference)
//
#include <hip/hip_runtime.h>
#include <math.h>

#define Bn   128
#define Ln   512
#define Hn   336
#define Dn   256
#define TXTn 768
#define Kn   16
#define EMBn 128
#define SHIFT 56      // max(1, H//6)
#define MSEB 1024
#define FROWS 48      // k_fposm rows per block (336/48 = 7)
#define FTILES 7
#define ASTRIDE 776   // 768 + 8 bf16 pad

typedef __attribute__((ext_vector_type(8))) short short8;
typedef __attribute__((ext_vector_type(4))) float floatx4;

__device__ __forceinline__ float softplusf(float x){
  return fmaxf(x, 0.f) + log1pf(expf(-fabsf(x)));
}
__device__ __forceinline__ unsigned short f2bf(float x){  // RNE f32 -> bf16 bits
  unsigned int u = __float_as_uint(x);
  unsigned int r = (u + 0x7fffu + ((u >> 16) & 1u)) >> 16;
  return (unsigned short)r;
}
__device__ __forceinline__ float rcpf(float x){ return __builtin_amdgcn_rcpf(x); }
__device__ __forceinline__ float wsum(float x){
  x += __shfl_xor(x, 1);  x += __shfl_xor(x, 2);  x += __shfl_xor(x, 4);
  x += __shfl_xor(x, 8);  x += __shfl_xor(x, 16); x += __shfl_xor(x, 32);
  return x;
}

// ---------- 1. fused: text->params, kappa, rr(normalized), ytir, ent/tv partials ----------
__global__ __launch_bounds__(256) void k_fused1(
    const float* __restrict__ text, const float* __restrict__ W, const float* __restrict__ bb,
    float* __restrict__ mu_o, float* __restrict__ kapT, float* __restrict__ rr_o,
    float* __restrict__ ytirs, float* __restrict__ part_ent, float* __restrict__ part_tv){
  int b = blockIdx.x, t = threadIdx.x;
  __shared__ float kapS[Kn*Hn];
  __shared__ float musL[Kn], sigL[Kn], ampL[Kn], shwL[Kn*4], entS[Kn], rrS[Kn];
  __shared__ float red[256];
  __shared__ float comb[112];
  __shared__ float totS;
  {
    int o = t & 127, half = t >> 7;      // lanes read consecutive W columns -> coalesced
    if (o < 112){
      const float* tb = text + (size_t)b*TXTn + half*384;
      const float* Wb = W + (size_t)half*384*112 + o;
      float a0=0.f, a1=0.f, a2=0.f, a3=0.f;
      for (int i = 0; i < 384; i += 4){
        float4 x = *(const float4*)(tb + i);
        a0 += x.x*Wb[(i+0)*112]; a1 += x.y*Wb[(i+1)*112];
        a2 += x.z*Wb[(i+2)*112]; a3 += x.w*Wb[(i+3)*112];
      }
      red[half*112 + o] = (a0 + a1) + (a2 + a3);
    }
  }
  __syncthreads();
  if (t < 112) comb[t] = red[t] + red[112 + t] + bb[t];
  __syncthreads();
  if (t < Kn){
    float r0 = comb[t*7+0], r1 = comb[t*7+1], r2 = comb[t*7+2];
    float mu  = 1.f/(1.f+expf(-r0));
    float sig = softplusf(r1)*0.15f + 1e-3f;
    float amp = softplusf(r2);
    float s0 = comb[t*7+3], s1 = comb[t*7+4], s2 = comb[t*7+5], s3 = comb[t*7+6];
    float m = fmaxf(fmaxf(s0,s1), fmaxf(s2,s3));
    float e0 = expf(s0-m), e1 = expf(s1-m), e2 = expf(s2-m), e3 = expf(s3-m);
    float inv = 1.f/(e0+e1+e2+e3);
    float w0 = e0*inv, w1 = e1*inv, w2 = e2*inv, w3 = e3*inv;
    musL[t] = mu; sigL[t] = sig; ampL[t] = amp;
    shwL[t*4+0] = w0; shwL[t*4+1] = w1; shwL[t*4+2] = w2; shwL[t*4+3] = w3;
    mu_o[b*Kn + t] = mu;
    float ent = 0.f, sw;
    sw = fmaxf(w0,1e-8f); ent += sw*logf(sw);
    sw = fmaxf(w1,1e-8f); ent += sw*logf(sw);
    sw = fmaxf(w2,1e-8f); ent += sw*logf(sw);
    sw = fmaxf(w3,1e-8f); ent += sw*logf(sw);
    entS[t] = ent;
  }
  __syncthreads();
  for (int p = t; p < Kn*Hn; p += 256){
    int k = p/Hn, h = p - k*Hn;
    float mu = musL[k], sig = sigL[k], amp = ampL[k];
    float w0 = shwL[k*4+0], w1 = shwL[k*4+1], w2 = shwL[k*4+2], w3 = shwL[k*4+3];
    float tt = (h + 0.5f)/(float)Hn;
    float z  = (tt - mu)/sig;
    float az = fabsf(z);
    float b0 = expf(-0.5f*z*z);
    float b1 = expf(-az);
    float b2 = fmaxf(1.f-az, 0.f);
    float zc = fminf(fmaxf(z,-1.f),1.f);
    float b3 = (az <= 1.f) ? 0.5f*(1.f+cosf(3.14159265358979f*zc)) : 0.f;
    kapS[p] = amp*(w0*b0 + w1*b1 + w2*b2 + w3*b3);
  }
  __syncthreads();
  for (int q = t; q < Kn*Hn; q += 256){
    int h = q >> 4, k = q & 15;
    kapT[((size_t)b*Hn + h)*Kn + k] = kapS[k*Hn + h];
  }
  {
    int k = t >> 4, j16 = t & 15;
    float s = 0.f;
    for (int h = j16; h < Hn; h += 16) s += kapS[k*Hn + h];
    red[t] = s;
  }
  __syncthreads();
  if (t < Kn){
    float s = 0.f;
    for (int j = 0; j < 16; ++j) s += red[t*16 + j];
    rrS[t] = s + 1e-6f;
  }
  __syncthreads();
  if (t == 0){
    float tot = 0.f, tv = 0.f, es = 0.f;
    for (int k = 0; k < Kn; ++k) tot += rrS[k];
    for (int k = 1; k < Kn; ++k) tv += fabsf(musL[k]-musL[k-1]);
    for (int k = 0; k < Kn; ++k) es += entS[k];
    totS = tot; part_tv[b] = tv; part_ent[b] = es;
  }
  __syncthreads();
  if (t < Kn) rr_o[b*Kn + t] = rrS[t]/totS;
  for (int h = t; h < Hn; h += 256){
    float s = 0.f;
    #pragma unroll
    for (int k = 0; k < Kn; ++k) s += kapS[k*Hn + h];
    ytirs[b*Hn + h] = s;
  }
}

// ---------- 2a. kemb stage 1: partial dots over 42-row h-chunks ----------
__global__ __launch_bounds__(128) void k_kemb1(const float* __restrict__ kapT,
    const float* __restrict__ W, float* __restrict__ kp){
  int blk = blockIdx.x;
  int b = blk >> 3, oc = blk & 7;
  int e = threadIdx.x;
  float acc[Kn];
  #pragma unroll
  for (int k = 0; k < Kn; ++k) acc[k] = 0.f;
  const float* kb = kapT + (size_t)b*Hn*Kn;
  int h0 = oc*42, h1 = h0 + 42;
  for (int h = h0; h < h1; ++h){
    float wv = W[h*EMBn + e];
    const float4* kr = (const float4*)(kb + h*Kn);   // wave-uniform -> s_load
    float4 c0 = kr[0], c1 = kr[1], c2 = kr[2], c3 = kr[3];
    acc[0]  += c0.x*wv; acc[1]  += c0.y*wv; acc[2]  += c0.z*wv; acc[3]  += c0.w*wv;
    acc[4]  += c1.x*wv; acc[5]  += c1.y*wv; acc[6]  += c1.z*wv; acc[7]  += c1.w*wv;
    acc[8]  += c2.x*wv; acc[9]  += c2.y*wv; acc[10] += c2.z*wv; acc[11] += c2.w*wv;
    acc[12] += c3.x*wv; acc[13] += c3.y*wv; acc[14] += c3.z*wv; acc[15] += c3.w*wv;
  }
  float* kpb = kp + ((size_t)blk*Kn)*EMBn + e;
  #pragma unroll
  for (int k = 0; k < Kn; ++k) kpb[(size_t)k*EMBn] = acc[k];
}

// ---------- 2b. kemb stage 2: combine 8 partials + bias, l2-normalize ----------
__global__ __launch_bounds__(256) void k_kemb2(const float* __restrict__ kp,
    const float* __restrict__ bb, float* __restrict__ kn_o){
  int b = blockIdx.x, t = threadIdx.x;
  __shared__ float kS[Kn*EMBn];
  __shared__ float r2[256];
  __shared__ float invS[Kn];
  for (int j = t; j < Kn*EMBn; j += 256){
    int e = j & 127;
    float s = bb[e];
    const float* p = kp + (size_t)b*8*Kn*EMBn + j;
    #pragma unroll
    for (int oc = 0; oc < 8; ++oc) s += p[(size_t)oc*Kn*EMBn];
    kS[j] = s;
  }
  __syncthreads();
  {
    int k = t & 15, g = t >> 4;       // 16 e-groups
    float s = 0.f;
    for (int e = g; e < EMBn; e += 16){ float v = kS[k*EMBn + e]; s += v*v; }
    r2[g*Kn + k] = s;
  }
  __syncthreads();
  if (t < Kn){
    float s = 0.f;
    for (int g = 0; g < 16; ++g) s += r2[g*Kn + t];
    invS[t] = 1.f/(sqrtf(s) + 1e-8f);
  }
  __syncthreads();
  for (int j = t; j < Kn*EMBn; j += 256)
    kn_o[(size_t)b*Kn*EMBn + j] = kS[j]*invS[j >> 7];
}

// ---------- 3. W_fp f32 [768][128] -> bf16 B-fragment-swizzled layout ----------
__global__ void k_wprep(const float* __restrict__ W, unsigned short* __restrict__ Bsw){
  int tid = blockIdx.x*256 + threadIdx.x;   // 98304 total
  int k = tid >> 7, n = tid & 127;
  int kt = k >> 5, kr = k & 31, quad = kr >> 3, j = kr & 7;
  int c = n >> 4, ln = n & 15;
  int lane = quad*16 + ln;
  int dst = ((kt*8 + c)*64 + lane)*8 + j;
  Bsw[dst] = f2bf(W[k*128 + n]);
}

// ---------- 4a. enc mean, stage 1: full-grid partial sums ----------
__global__ __launch_bounds__(256) void k_encmean(const float* __restrict__ enc,
                                                 float* __restrict__ psum){
  int blk = blockIdx.x;
  int b = blk >> 3, p = blk & 7;
  int t = threadIdx.x;
  int d4 = t & 63, rg = t >> 6;    // 4 row-groups
  const float4* e4 = (const float4*)(enc + (size_t)b*Ln*Dn);
  float4 s = make_float4(0.f,0.f,0.f,0.f);
  for (int l = p + 8*rg; l < Ln; l += 32){
    float4 v = e4[(size_t)l*64 + d4];
    s.x += v.x; s.y += v.y; s.z += v.z; s.w += v.w;
  }
  __shared__ float4 red[256];
  red[t] = s;
  __syncthreads();
  if (rg == 0){
    float4 o = red[d4];
    #pragma unroll
    for (int r = 1; r < 4; ++r){
      float4 v = red[r*64 + d4];
      o.x += v.x; o.y += v.y; o.z += v.z; o.w += v.w;
    }
    ((float4*)(psum + ((size_t)b*8 + p)*Dn))[d4] = o;
  }
}

// ---------- 4b. gate MLP layer 1, k-split x4: partial dots over a 320-slice ----------
__global__ __launch_bounds__(256) void k_gmlp1(const float* __restrict__ psum,
    const float* __restrict__ text, const float* __restrict__ vp,
    const float* __restrict__ W1, float* __restrict__ hidp){
  int bt = blockIdx.x >> 5, hc = (blockIdx.x >> 2) & 7, ks = blockIdx.x & 3;
  int t = threadIdx.x;
  __shared__ float inS[4][320];
  for (int j = t; j < 4*320; j += 256){
    int bi = j / 320, jj = j - bi*320;
    int gi = ks*320 + jj;
    int b = bt*4 + bi;
    float vsl;
    if (gi < Dn){
      float s = 0.f;
      for (int p = 0; p < 8; ++p) s += psum[((size_t)b*8 + p)*Dn + gi];
      vsl = s * (1.f/(float)Ln);
    } else if (gi < Dn + TXTn){
      vsl = text[(size_t)b*TXTn + (gi - Dn)];
    } else {
      vsl = vp[gi - Dn - TXTn];
    }
    inS[bi][jj] = vsl;
  }
  __syncthreads();
  int h = t & 63, bi = t >> 6;                  // wave-uniform bi -> LDS broadcast
  int hidx = hc*64 + h;
  const float* Wb = W1 + (size_t)(ks*320)*512 + hidx;
  float a0 = 0.f, a1 = 0.f, a2 = 0.f, a3 = 0.f;
  const float4* in4 = (const float4*)inS[bi];
  for (int i = 0; i < 320; i += 4){
    float4 x = in4[i >> 2];
    a0 += x.x*Wb[(size_t)(i+0)*512]; a1 += x.y*Wb[(size_t)(i+1)*512];
    a2 += x.z*Wb[(size_t)(i+2)*512]; a3 += x.w*Wb[(size_t)(i+3)*512];
  }
  hidp[((size_t)ks*Bn + bt*4 + bi)*512 + hidx] = (a0 + a1) + (a2 + a3);
}

// ---------- 4c. gate MLP layer 2: 256 blocks, 64-deep chains, 4-way bi ILP ----------
__global__ __launch_bounds__(256) void k_gmlp2(const float* __restrict__ hidp,
    const float* __restrict__ b1, const float* __restrict__ W2,
    const float* __restrict__ b2, float* __restrict__ gate_o){
  int bt = blockIdx.x >> 3, dc = blockIdx.x & 7;
  int t = threadIdx.x;
  __shared__ float hS[4][512];
  __shared__ float pS[8][4][32];
  for (int j = t; j < 4*512; j += 256){
    int bi = j >> 9, i = j & 511;
    size_t bidx = (size_t)(bt*4 + bi)*512 + i;
    float s = hidp[bidx] + hidp[(size_t)Bn*512 + bidx]
            + hidp[(size_t)2*Bn*512 + bidx] + hidp[(size_t)3*Bn*512 + bidx];
    hS[bi][i] = fmaxf(s + b1[i], 0.f);
  }
  __syncthreads();
  {
    int dl = t & 31, ig = t >> 5;       // 32 d x 8 i-groups
    int d  = dc*32 + dl;
    float a0=0.f, a1=0.f, a2=0.f, a3=0.f;
    int i0 = ig*64;
    for (int i = i0; i < i0 + 64; ++i){
      float wv = W2[(size_t)i*Dn + d];
      a0 += hS[0][i]*wv; a1 += hS[1][i]*wv;
      a2 += hS[2][i]*wv; a3 += hS[3][i]*wv;
    }
    pS[ig][0][dl] = a0; pS[ig][1][dl] = a1;
    pS[ig][2][dl] = a2; pS[ig][3][dl] = a3;
  }
  __syncthreads();
  if (t < 128){
    int bi = t >> 5, dl = t & 31;
    float s = 0.f;
    #pragma unroll
    for (int g = 0; g < 8; ++g) s += pS[g][bi][dl];
    s += b2[dc*32 + dl];
    gate_o[(size_t)(bt*4 + bi)*Dn + dc*32 + dl] = 1.f/(1.f + expf(-s));
  }
}

// ---------- 5. f_pos via bf16 MFMA ----------
__global__ __launch_bounds__(256) void k_fposm(const float* __restrict__ yf,
    const unsigned short* __restrict__ Bsw, const float* __restrict__ bb,
    float* __restrict__ fpos, float* __restrict__ finv){
  int b = blockIdx.x / FTILES, tile = blockIdx.x % FTILES;
  int t = threadIdx.x;
  int h0 = tile*FROWS;
  __shared__ unsigned short yS[FROWS*ASTRIDE];
  __shared__ float rsq[4][FROWS];
  const float* yb = yf + (size_t)b*Hn*Dn;

  #pragma unroll
  for (int u = 0; u < 12; ++u){
    int unit = t + 256*u;
    int r = unit >> 6, d4 = unit & 63;
    int h = h0 + r;
    int hm1 = h-1 < 0 ? 0 : h-1;
    int hm2 = h-2 < 0 ? 0 : h-2;
    float4 y   = *(const float4*)(yb + (size_t)h  *Dn + d4*4);
    float4 ym1 = *(const float4*)(yb + (size_t)hm1*Dn + d4*4);
    float4 ym2 = *(const float4*)(yb + (size_t)hm2*Dn + d4*4);
    float4 d1 = make_float4(y.x-ym1.x, y.y-ym1.y, y.z-ym1.z, y.w-ym1.w);
    float4 d2 = make_float4(y.x-2.f*ym1.x+ym2.x, y.y-2.f*ym1.y+ym2.y,
                            y.z-2.f*ym1.z+ym2.z, y.w-2.f*ym1.w+ym2.w);
    union { unsigned short u16[4]; uint2 v; } p;
    unsigned short* base = &yS[r*ASTRIDE + d4*4];
    p.u16[0]=f2bf(y.x);  p.u16[1]=f2bf(y.y);  p.u16[2]=f2bf(y.z);  p.u16[3]=f2bf(y.w);
    *(uint2*)(base)        = p.v;
    p.u16[0]=f2bf(d1.x); p.u16[1]=f2bf(d1.y); p.u16[2]=f2bf(d1.z); p.u16[3]=f2bf(d1.w);
    *(uint2*)(base + 256)  = p.v;
    p.u16[0]=f2bf(d2.x); p.u16[1]=f2bf(d2.y); p.u16[2]=f2bf(d2.z); p.u16[3]=f2bf(d2.w);
    *(uint2*)(base + 512)  = p.v;
  }
  __syncthreads();

  int wv   = __builtin_amdgcn_readfirstlane(t >> 6);
  int lane = t & 63, quad = lane >> 4, ln = lane & 15;
  int c0 = wv*2;
  floatx4 acc[3][2];
  #pragma unroll
  for (int i = 0; i < 3; ++i){
    acc[i][0] = (floatx4){0.f,0.f,0.f,0.f};
    acc[i][1] = (floatx4){0.f,0.f,0.f,0.f};
  }
  #pragma unroll
  for (int kt = 0; kt < 24; ++kt){
    int aoff = kt*32 + quad*8;
    short8 a0 = *(const short8*)&yS[( 0 + ln)*ASTRIDE + aoff];
    short8 a1 = *(const short8*)&yS[(16 + ln)*ASTRIDE + aoff];
    short8 a2 = *(const short8*)&yS[(32 + ln)*ASTRIDE + aoff];
    short8 b0 = *(const short8*)&Bsw[((kt*8 + c0  )*64 + lane)*8];
    short8 b1 = *(const short8*)&Bsw[((kt*8 + c0+1)*64 + lane)*8];
    acc[0][0] = __builtin_amdgcn_mfma_f32_16x16x32_bf16(a0, b0, acc[0][0], 0, 0, 0);
    acc[0][1] = __builtin_amdgcn_mfma_f32_16x16x32_bf16(a0, b1, acc[0][1], 0, 0, 0);
    acc[1][0] = __builtin_amdgcn_mfma_f32_16x16x32_bf16(a1, b0, acc[1][0], 0, 0, 0);
    acc[1][1] = __builtin_amdgcn_mfma_f32_16x16x32_bf16(a1, b1, acc[1][1], 0, 0, 0);
    acc[2][0] = __builtin_amdgcn_mfma_f32_16x16x32_bf16(a2, b0, acc[2][0], 0, 0, 0);
    acc[2][1] = __builtin_amdgcn_mfma_f32_16x16x32_bf16(a2, b1, acc[2][1], 0, 0, 0);
  }

  float bias0 = bb[c0*16 + ln], bias1 = bb[(c0+1)*16 + ln];
  #pragma unroll
  for (int rt = 0; rt < 3; ++rt){
    #pragma unroll
    for (int reg = 0; reg < 4; ++reg){
      int lrow = rt*16 + quad*4 + reg;
      size_t row = (size_t)b*Hn + h0 + lrow;
      float v0 = acc[rt][0][reg] + bias0;
      float v1 = acc[rt][1][reg] + bias1;
      fpos[row*EMBn + c0*16 + ln]     = v0;
      fpos[row*EMBn + (c0+1)*16 + ln] = v1;
      float sq = v0*v0 + v1*v1;
      sq += __shfl_xor(sq, 1); sq += __shfl_xor(sq, 2);
      sq += __shfl_xor(sq, 4); sq += __shfl_xor(sq, 8);
      if (ln == 0) rsq[wv][lrow] = sq;
    }
  }
  __syncthreads();
  if (t < FROWS){
    float s = rsq[0][t] + rsq[1][t] + rsq[2][t] + rsq[3][t];
    finv[(size_t)b*Hn + h0 + t] = 1.f/(sqrtf(s) + 1e-8f);
  }
}

// ---------- 6. MSE of gated fusion ----------
__global__ void k_mse(const float* __restrict__ yres, const float* __restrict__ yfut,
                      const float* __restrict__ gate, const float* __restrict__ ytirs,
                      const float* __restrict__ Wt, const float* __restrict__ bt,
                      const float* __restrict__ vp, float* __restrict__ part_mse){
  const long long total = (long long)Bn*Hn*Dn;
  long long tid = blockIdx.x*(long long)blockDim.x + threadIdx.x;
  long long nth = gridDim.x*(long long)blockDim.x;
  float part = 0.f;
  for (long long i4 = tid; i4*4 < total; i4 += nth){
    long long base = i4*4;
    int b = (int)(base/((long long)Hn*Dn));
    int rem = (int)(base - (long long)b*Hn*Dn);
    int h = rem/Dn, d = rem - h*Dn;
    float4 yr = *(const float4*)(yres + base);
    float4 yv = *(const float4*)(yfut + base);
    float4 g  = *(const float4*)(gate + (size_t)b*Dn + d);
    float4 wt = *(const float4*)(Wt + d);
    float4 bv = *(const float4*)(bt + d);
    float4 vv = *(const float4*)(vp + d);
    float ys = ytirs[b*Hn + h];
    float yt, yh, e;
    yt = (ys*wt.x + bv.x)*vv.x; yh = yr.x + 0.5f*g.x*(yt-yr.x); e = yh-yv.x; part += e*e;
    yt = (ys*wt.y + bv.y)*vv.y; yh = yr.y + 0.5f*g.y*(yt-yr.y); e = yh-yv.y; part += e*e;
    yt = (ys*wt.z + bv.z)*vv.z; yh = yr.z + 0.5f*g.z*(yt-yr.z); e = yh-yv.z; part += e*e;
    yt = (ys*wt.w + bv.w)*vv.w; yh = yr.w + 0.5f*g.w*(yt-yr.w); e = yh-yv.w; part += e*e;
  }
  __shared__ float red[256];
  red[threadIdx.x] = part; __syncthreads();
  for (int s = 128; s > 0; s >>= 1){
    if (threadIdx.x < s) red[threadIdx.x] += red[threadIdx.x + s];
    __syncthreads();
  }
  if (threadIdx.x == 0) part_mse[blockIdx.x] = red[0];
}

// ---------- 7a. cost: Km[b][k][h] = exp(-20*C), h-split over 4 blocks ----------
__global__ __launch_bounds__(256) void k_cost(const float* __restrict__ kn,
    const float* __restrict__ fpos, const float* __restrict__ finv,
    const float* __restrict__ mu_i, float* __restrict__ Km_g){
  int b = blockIdx.x >> 2, q = blockIdx.x & 3;
  int t = threadIdx.x;
  __shared__ float knS[Kn*132];
  __shared__ float musS[Kn];
  for (int j = t; j < Kn*EMBn; j += 256){
    int k = j >> 7, e = j & 127;
    knS[k*132 + e] = kn[(size_t)b*Kn*EMBn + j];
  }
  if (t < Kn) musS[t] = mu_i[b*Kn + t];
  __syncthreads();
  const int H0 = q*84;
  for (int p = t; p < Kn*84; p += 256){
    int k = p & 15, h = H0 + (p >> 4);
    const float4* f4 = (const float4*)(fpos + ((size_t)b*Hn + h)*EMBn);
    const float4* k4 = (const float4*)(knS + k*132);
    float s = 0.f;
    #pragma unroll 8
    for (int i = 0; i < EMBn/4; ++i){
      float4 a = k4[i], f = f4[i];
      s += a.x*f.x + a.y*f.y + a.z*f.z + a.w*f.w;
    }
    float cs = s*finv[b*Hn + h];
    float th = (h + 0.5f)/(float)Hn;
    float c  = (1.f - cs) + 0.5f*fmaxf(musS[k] - th, 0.f);
    Km_g[(size_t)b*Kn*Hn + k*Hn + h] = expf(-20.f*c);
  }
}

// ---------- 7b. Sinkhorn: Km fully LDS-resident, 256 threads, no register arrays ----------
// u-phase: 16 threads per k (21 h's each + 4-step shfl); v-phase: 1-2 h per thread x 16 k.
// tail: wT[k][h] = Km*v/dot[k] (u cancels in row normalization).
__global__ __launch_bounds__(256) void k_sink(const float* __restrict__ rr,
    float* KmwT, float* __restrict__ part_cot){
  int b = blockIdx.x, t = threadIdx.x;
  float* Kb = KmwT + (size_t)b*Kn*Hn;
  __shared__ float KmS[Kn*Hn];    // 21504 B
  __shared__ float uS[Kn], vS[Hn], dotS[Kn], rrS[Kn];
  __shared__ float redc[4];
  for (int j = t; j < Kn*Hn; j += 256) KmS[j] = Kb[j];
  for (int h = t; h < Hn; h += 256) vS[h] = 1.f;
  if (t < Kn) rrS[t] = rr[b*Kn + t];
  __syncthreads();
  const int kk = t >> 4, hl = t & 15;
  for (int it = 0; it < 30; ++it){
    // u-phase: u[k] = rr[k] / sum_h Km[k][h]*v[h]
    float s = 0.f;
    for (int h = hl; h < Hn; h += 16) s += KmS[kk*Hn + h]*vS[h];
    s += __shfl_xor(s, 1); s += __shfl_xor(s, 2);
    s += __shfl_xor(s, 4); s += __shfl_xor(s, 8);
    if (hl == 0) uS[kk] = rrS[kk]*rcpf(s + 1e-9f);
    __syncthreads();
    // v-phase: v[h] = (1/H) / sum_k Km[k][h]*u[k]
    for (int h = t; h < Hn; h += 256){
      float sv = 0.f;
      #pragma unroll
      for (int k = 0; k < Kn; ++k) sv += KmS[k*Hn + h]*uS[k];
      vS[h] = (1.f/(float)Hn)*rcpf(sv + 1e-9f);
    }
    __syncthreads();
  }
  // dot[k] with final v (Pi row-sum = u[k]*dot[k])
  {
    float s = 0.f;
    for (int h = hl; h < Hn; h += 16) s += KmS[kk*Hn + h]*vS[h];
    s += __shfl_xor(s, 1); s += __shfl_xor(s, 2);
    s += __shfl_xor(s, 4); s += __shfl_xor(s, 8);
    if (hl == 0) dotS[kk] = s;
  }
  __syncthreads();
  // cot + wT write: Pi = u*Km*v; wT = Pi/(u*dot) = Km*v/dot
  float cot = 0.f;
  #pragma unroll
  for (int k = 0; k < Kn; ++k){
    float uk = uS[k], dinv = rcpf(dotS[k] + 1e-30f);
    for (int h = t; h < Hn; h += 256){
      float kmv = KmS[k*Hn + h];
      float Pi = uk*kmv*vS[h];
      cot += (-0.05f)*logf(kmv)*Pi;     // C = -eps*ln(Km)
      Kb[k*Hn + h] = kmv*vS[h]*dinv;    // wT[b][k][h]
    }
  }
  cot = wsum(cot);
  if ((t & 63) == 0) redc[t >> 6] = cot;
  __syncthreads();
  if (t == 0) part_cot[b] = redc[0] + redc[1] + redc[2] + redc[3];
}

// ---------- 7c. agg + delta-contrastive, k-quad split x4, h-halves inside ----------
__global__ __launch_bounds__(256) void k_agg(const float* __restrict__ kn,
    const float* __restrict__ fpos, const float* __restrict__ wT,
    const int* __restrict__ perm, float* __restrict__ part_del4){
  int b = blockIdx.x >> 2, kg = blockIdx.x & 3;   // 4 k's per block
  int t = threadIdx.x;
  __shared__ float wTl[Hn*4];           // k inner (16B rows, broadcast reads)
  __shared__ float apH[2][4*EMBn];
  __shared__ float a1H[2][4*EMBn];
  __shared__ int permS[EMBn];
  __shared__ float redW[4];
  if (t < EMBn) permS[t] = perm[t];
  for (int j = t; j < 4*Hn; j += 256){
    int k = j & 3, h = j >> 2;
    wTl[h*4 + k] = wT[(size_t)b*Kn*Hn + (size_t)(kg*4 + k)*Hn + h];
  }
  __syncthreads();

  {
    int e = t & 127, jh = t >> 7;       // jh: h-half (168 each)
    float ap[4], a1[4];
    #pragma unroll
    for (int j = 0; j < 4; ++j){ ap[j] = 0.f; a1[j] = 0.f; }
    const float* fb = fpos + (size_t)b*Hn*EMBn + e;
    int hh0 = jh*168, hh1 = hh0 + 168;
    for (int h = hh0; h < hh1; ++h){
      float fv = fb[(size_t)h*EMBn];
      int h1 = h + SHIFT; if (h1 >= Hn) h1 -= Hn;
      float4 wA = *(const float4*)&wTl[h *4];
      float4 wB = *(const float4*)&wTl[h1*4];
      ap[0] += wA.x*fv; ap[1] += wA.y*fv; ap[2] += wA.z*fv; ap[3] += wA.w*fv;
      a1[0] += wB.x*fv; a1[1] += wB.y*fv; a1[2] += wB.z*fv; a1[3] += wB.w*fv;
    }
    #pragma unroll
    for (int j = 0; j < 4; ++j){
      apH[jh][j*EMBn + e] = ap[j];
      a1H[jh][j*EMBn + e] = a1[j];
    }
  }
  __syncthreads();
  for (int j = t; j < 4*EMBn; j += 256){
    apH[0][j] += apH[1][j];
    a1H[0][j] += a1H[1][j];
  }
  __syncthreads();

  int wave = t >> 6, lane = t & 63;
  {
    int kl = wave;                      // 1 k per wave
    int k  = kg*4 + kl;
    float sp = 0.f, s1 = 0.f, s2 = 0.f, np = 0.f, n1 = 0.f;
    for (int e = lane; e < EMBn; e += 64){
      float kne = kn[((size_t)b*Kn + k)*EMBn + e];
      float a  = apH[0][kl*EMBn + e];
      float c1 = a1H[0][kl*EMBn + e];
      sp += kne*a; s1 += kne*c1;
      s2 += kne*apH[0][kl*EMBn + permS[e]];
      np += a*a; n1 += c1*c1;
    }
    for (int o = 32; o; o >>= 1){
      sp += __shfl_down(sp, o); s1 += __shfl_down(s1, o); s2 += __shfl_down(s2, o);
      np += __shfl_down(np, o); n1 += __shfl_down(n1, o);
    }
    if (lane == 0){
      float ip  = 1.f/(sqrtf(np) + 1e-8f);
      float i1v = 1.f/(sqrtf(n1) + 1e-8f);
      const float ti = 1.f/0.07f;
      float l0 = sp*ip*ti, l1 = s1*i1v*ti, l2 = s2*ip*ti;
      float m = fmaxf(l0, fmaxf(l1, l2));
      float lse = m + logf(expf(l0-m) + expf(l1-m) + expf(l2-m));
      redW[wave] = lse - l0;
    }
  }
  __syncthreads();
  if (t == 0) part_del4[(size_t)b*4 + kg] = redW[0] + redW[1] + redW[2] + redW[3];
}

// ---------- 8. combine ----------
__global__ void k_final(const float* __restrict__ part_mse, const float* __restrict__ part_cot,
                        const float* __restrict__ part_del4, const float* __restrict__ part_ent,
                        const float* __restrict__ part_tv, float* __restrict__ out){
  int t = threadIdx.x;  // 256
  __shared__ double sred[256];
  double m = 0.0;
  for (int i = t; i < MSEB; i += 256) m += (double)part_mse[i];
  double o4 = 0.0;
  if (t < Bn){
    double del = (double)part_del4[4*t] + (double)part_del4[4*t + 1]
               + (double)part_del4[4*t + 2] + (double)part_del4[4*t + 3];
    o4 = 0.1*(double)part_cot[t] + (0.1/(double)Kn)*del
       - (0.01/(double)Kn)*(double)part_ent[t] + (0.01/(double)(Kn-1))*(double)part_tv[t];
  }
  sred[t] = m/((double)Bn*Hn*Dn) + o4/(double)Bn;
  __syncthreads();
  for (int s = 128; s > 0; s >>= 1){ if (t < s) sred[t] += sred[t+s]; __syncthreads(); }
  if (t == 0) out[0] = (float)sred[0];
}

// ---------- launch ----------
extern "C" void kernel_launch(void* const* d_in, const int* in_sizes, int n_in,
                              void* d_out, int out_size, void* d_ws, size_t ws_size,
                              hipStream_t stream) {
  const float* y_res  = (const float*)d_in[0];
  const float* text   = (const float*)d_in[1];
  const float* enc    = (const float*)d_in[2];
  const float* yfut   = (const float*)d_in[3];
  const int*   perm   = (const int*)  d_in[4];
  const float* W_t2k  = (const float*)d_in[5];
  const float* b_t2k  = (const float*)d_in[6];
  const float* W_kemb = (const float*)d_in[7];
  const float* b_kemb = (const float*)d_in[8];
  const float* W_tir  = (const float*)d_in[9];
  const float* b_tir  = (const float*)d_in[10];
  const float* vproj  = (const float*)d_in[11];
  const float* W_g1   = (const float*)d_in[12];
  const float* b_g1   = (const float*)d_in[13];
  const float* W_g2   = (const float*)d_in[14];
  const float* b_g2   = (const float*)d_in[15];
  const float* W_fp   = (const float*)d_in[16];
  const float* b_fp   = (const float*)d_in[17];

  float* F = (float*)d_ws;
  float* mu_w   = F;            // 2048
  float* rr_w   = F + 2048;     // 2048
  float* ytr_w  = F + 4096;     // 43008
  float* kapT_w = F + 47104;    // 688128  (lifecycle: kapT -> Bsw -> Km -> wT)
  float* kn_w   = F + 735232;   // 262144
  float* gate_w = F + 997376;   // 32768  (lifecycle: gate -> part_del4)
  float* fp_w   = F + 1030144;  // 5505024
  float* fi_w   = F + 6535168;  // 43008
  float* pmse_w = F + 6578176;  // 1024
  float* pcot_w = F + 6579200;  // 128
  float* pent_w = F + 6579456;  // 128
  float* ptv_w  = F + 6579584;  // 128
  unsigned short* Bsw_w = (unsigned short*)kapT_w;  // 192 KB, dead after k_fposm
  float* KmwT_w = kapT_w;                            // 2.75 MB, exact-size overlay
  // scratch overlays on fp_w (dead until k_fposm writes it), lifetimes sequential:
  float* kp_w   = fp_w;             // 8*128*16*128 = 2097152 floats (kemb partials)
  float* psum_w = fp_w;             // 128*8*256 = 262144 floats (after kemb2)
  float* hidp_w = fp_w + 262144;    // 4*128*512 = 262144 floats (layer-1 partials)
  // part_del4 overlays gate_w (gate dead after k_mse; k_agg runs after k_mse):
  float* pdel4_w = gate_w;          // 512 floats

  k_fused1 <<<Bn, 256, 0, stream>>>(text, W_t2k, b_t2k, mu_w, kapT_w, rr_w, ytr_w, pent_w, ptv_w);
  k_kemb1  <<<Bn*8, 128, 0, stream>>>(kapT_w, W_kemb, kp_w);
  k_kemb2  <<<Bn, 256, 0, stream>>>(kp_w, b_kemb, kn_w);
  k_wprep  <<<384, 256, 0, stream>>>(W_fp, Bsw_w);
  k_encmean<<<Bn*8, 256, 0, stream>>>(enc, psum_w);
  k_gmlp1  <<<1024, 256, 0, stream>>>(psum_w, text, vproj, W_g1, hidp_w);
  k_gmlp2  <<<256, 256, 0, stream>>>(hidp_w, b_g1, W_g2, b_g2, gate_w);
  k_fposm  <<<Bn*FTILES, 256, 0, stream>>>(yfut, Bsw_w, b_fp, fp_w, fi_w);
  k_mse    <<<MSEB, 256, 0, stream>>>(y_res, yfut, gate_w, ytr_w, W_tir, b_tir, vproj, pmse_w);
  k_cost   <<<Bn*4, 256, 0, stream>>>(kn_w, fp_w, fi_w, mu_w, KmwT_w);
  k_sink   <<<Bn, 256, 0, stream>>>(rr_w, KmwT_w, pcot_w);
  k_agg    <<<Bn*4, 256, 0, stream>>>(kn_w, fp_w, KmwT_w, perm, pdel4_w);
  k_final  <<<1, 256, 0, stream>>>(pmse_w, pcot_w, pdel4_w, pent_w, ptv_w, (float*)d_out);
}

// Round 8
// 326.224 us; speedup vs baseline: 1.1295x; 1.1295x over previous
//
#include <hip/hip_runtime.h>
#include <math.h>

#define Bn   128
#define Ln   512
#define Hn   336
#define Dn   256
#define TXTn 768
#define Kn   16
#define EMBn 128
#define SHIFT 56      // max(1, H//6)
#define MSEB 1024
#define FROWS 48      // fposm rows per block (336/48 = 7)
#define FTILES 7
#define ASTRIDE 776   // 768 + 8 bf16 pad

typedef __attribute__((ext_vector_type(8))) short short8;
typedef __attribute__((ext_vector_type(4))) float floatx4;

__device__ __forceinline__ float softplusf(float x){
  return fmaxf(x, 0.f) + log1pf(expf(-fabsf(x)));
}
__device__ __forceinline__ unsigned short f2bf(float x){  // RNE f32 -> bf16 bits
  unsigned int u = __float_as_uint(x);
  unsigned int r = (u + 0x7fffu + ((u >> 16) & 1u)) >> 16;
  return (unsigned short)r;
}
__device__ __forceinline__ float rcpf(float x){ return __builtin_amdgcn_rcpf(x); }
__device__ __forceinline__ float wsum(float x){
  x += __shfl_xor(x, 1);  x += __shfl_xor(x, 2);  x += __shfl_xor(x, 4);
  x += __shfl_xor(x, 8);  x += __shfl_xor(x, 16); x += __shfl_xor(x, 32);
  return x;
}

// ---------- 1. fused: text->params, kappa, rr(normalized), ytir, ent/tv partials ----------
__global__ __launch_bounds__(256) void k_fused1(
    const float* __restrict__ text, const float* __restrict__ W, const float* __restrict__ bb,
    float* __restrict__ mu_o, float* __restrict__ kapT, float* __restrict__ rr_o,
    float* __restrict__ ytirs, float* __restrict__ part_ent, float* __restrict__ part_tv){
  int b = blockIdx.x, t = threadIdx.x;
  __shared__ float kapS[Kn*Hn];
  __shared__ float musL[Kn], sigL[Kn], ampL[Kn], shwL[Kn*4], entS[Kn], rrS[Kn];
  __shared__ float red[256];
  __shared__ float comb[112];
  __shared__ float totS;
  {
    int o = t & 127, half = t >> 7;      // lanes read consecutive W columns -> coalesced
    if (o < 112){
      const float* tb = text + (size_t)b*TXTn + half*384;
      const float* Wb = W + (size_t)half*384*112 + o;
      float a0=0.f, a1=0.f, a2=0.f, a3=0.f;
      for (int i = 0; i < 384; i += 4){
        float4 x = *(const float4*)(tb + i);
        a0 += x.x*Wb[(i+0)*112]; a1 += x.y*Wb[(i+1)*112];
        a2 += x.z*Wb[(i+2)*112]; a3 += x.w*Wb[(i+3)*112];
      }
      red[half*112 + o] = (a0 + a1) + (a2 + a3);
    }
  }
  __syncthreads();
  if (t < 112) comb[t] = red[t] + red[112 + t] + bb[t];
  __syncthreads();
  if (t < Kn){
    float r0 = comb[t*7+0], r1 = comb[t*7+1], r2 = comb[t*7+2];
    float mu  = 1.f/(1.f+expf(-r0));
    float sig = softplusf(r1)*0.15f + 1e-3f;
    float amp = softplusf(r2);
    float s0 = comb[t*7+3], s1 = comb[t*7+4], s2 = comb[t*7+5], s3 = comb[t*7+6];
    float m = fmaxf(fmaxf(s0,s1), fmaxf(s2,s3));
    float e0 = expf(s0-m), e1 = expf(s1-m), e2 = expf(s2-m), e3 = expf(s3-m);
    float inv = 1.f/(e0+e1+e2+e3);
    float w0 = e0*inv, w1 = e1*inv, w2 = e2*inv, w3 = e3*inv;
    musL[t] = mu; sigL[t] = sig; ampL[t] = amp;
    shwL[t*4+0] = w0; shwL[t*4+1] = w1; shwL[t*4+2] = w2; shwL[t*4+3] = w3;
    mu_o[b*Kn + t] = mu;
    float ent = 0.f, sw;
    sw = fmaxf(w0,1e-8f); ent += sw*logf(sw);
    sw = fmaxf(w1,1e-8f); ent += sw*logf(sw);
    sw = fmaxf(w2,1e-8f); ent += sw*logf(sw);
    sw = fmaxf(w3,1e-8f); ent += sw*logf(sw);
    entS[t] = ent;
  }
  __syncthreads();
  for (int p = t; p < Kn*Hn; p += 256){
    int k = p/Hn, h = p - k*Hn;
    float mu = musL[k], sig = sigL[k], amp = ampL[k];
    float w0 = shwL[k*4+0], w1 = shwL[k*4+1], w2 = shwL[k*4+2], w3 = shwL[k*4+3];
    float tt = (h + 0.5f)/(float)Hn;
    float z  = (tt - mu)/sig;
    float az = fabsf(z);
    float b0 = expf(-0.5f*z*z);
    float b1 = expf(-az);
    float b2 = fmaxf(1.f-az, 0.f);
    float zc = fminf(fmaxf(z,-1.f),1.f);
    float b3 = (az <= 1.f) ? 0.5f*(1.f+cosf(3.14159265358979f*zc)) : 0.f;
    kapS[p] = amp*(w0*b0 + w1*b1 + w2*b2 + w3*b3);
  }
  __syncthreads();
  for (int q = t; q < Kn*Hn; q += 256){
    int h = q >> 4, k = q & 15;
    kapT[((size_t)b*Hn + h)*Kn + k] = kapS[k*Hn + h];
  }
  {
    int k = t >> 4, j16 = t & 15;
    float s = 0.f;
    for (int h = j16; h < Hn; h += 16) s += kapS[k*Hn + h];
    red[t] = s;
  }
  __syncthreads();
  if (t < Kn){
    float s = 0.f;
    for (int j = 0; j < 16; ++j) s += red[t*16 + j];
    rrS[t] = s + 1e-6f;
  }
  __syncthreads();
  if (t == 0){
    float tot = 0.f, tv = 0.f, es = 0.f;
    for (int k = 0; k < Kn; ++k) tot += rrS[k];
    for (int k = 1; k < Kn; ++k) tv += fabsf(musL[k]-musL[k-1]);
    for (int k = 0; k < Kn; ++k) es += entS[k];
    totS = tot; part_tv[b] = tv; part_ent[b] = es;
  }
  __syncthreads();
  if (t < Kn) rr_o[b*Kn + t] = rrS[t]/totS;
  for (int h = t; h < Hn; h += 256){
    float s = 0.f;
    #pragma unroll
    for (int k = 0; k < Kn; ++k) s += kapS[k*Hn + h];
    ytirs[b*Hn + h] = s;
  }
}

// ---------- 2. kemb stage 1: partial dots over 42-row h-chunks ----------
__global__ __launch_bounds__(128) void k_kemb1(const float* __restrict__ kapT,
    const float* __restrict__ W, float* __restrict__ kp){
  int blk = blockIdx.x;
  int b = blk >> 3, oc = blk & 7;
  int e = threadIdx.x;
  float acc[Kn];
  #pragma unroll
  for (int k = 0; k < Kn; ++k) acc[k] = 0.f;
  const float* kb = kapT + (size_t)b*Hn*Kn;
  int h0 = oc*42, h1 = h0 + 42;
  for (int h = h0; h < h1; ++h){
    float wv = W[h*EMBn + e];
    const float4* kr = (const float4*)(kb + h*Kn);   // wave-uniform -> s_load
    float4 c0 = kr[0], c1 = kr[1], c2 = kr[2], c3 = kr[3];
    acc[0]  += c0.x*wv; acc[1]  += c0.y*wv; acc[2]  += c0.z*wv; acc[3]  += c0.w*wv;
    acc[4]  += c1.x*wv; acc[5]  += c1.y*wv; acc[6]  += c1.z*wv; acc[7]  += c1.w*wv;
    acc[8]  += c2.x*wv; acc[9]  += c2.y*wv; acc[10] += c2.z*wv; acc[11] += c2.w*wv;
    acc[12] += c3.x*wv; acc[13] += c3.y*wv; acc[14] += c3.z*wv; acc[15] += c3.w*wv;
  }
  float* kpb = kp + ((size_t)blk*Kn)*EMBn + e;
  #pragma unroll
  for (int k = 0; k < Kn; ++k) kpb[(size_t)k*EMBn] = acc[k];
}

// ---------- 3. MERGED: kemb2(128) | wprep(384) | encmean(1024) ----------
__global__ __launch_bounds__(256) void k_p3(const float* __restrict__ kp,
    const float* __restrict__ bkemb, float* __restrict__ kn_o,
    const float* __restrict__ Wfp, unsigned short* __restrict__ Bsw,
    const float* __restrict__ enc, float* __restrict__ psum){
  int blk = blockIdx.x, t = threadIdx.x;
  __shared__ float kS[Kn*EMBn];
  __shared__ float r2[256];
  __shared__ float invS[Kn];
  __shared__ float4 redE[256];
  if (blk < 128){
    // ---- kemb2 ----
    int b = blk;
    for (int j = t; j < Kn*EMBn; j += 256){
      int e = j & 127;
      float s = bkemb[e];
      const float* p = kp + (size_t)b*8*Kn*EMBn + j;
      #pragma unroll
      for (int oc = 0; oc < 8; ++oc) s += p[(size_t)oc*Kn*EMBn];
      kS[j] = s;
    }
    __syncthreads();
    {
      int k = t & 15, g = t >> 4;
      float s = 0.f;
      for (int e = g; e < EMBn; e += 16){ float v = kS[k*EMBn + e]; s += v*v; }
      r2[g*Kn + k] = s;
    }
    __syncthreads();
    if (t < Kn){
      float s = 0.f;
      for (int g = 0; g < 16; ++g) s += r2[g*Kn + t];
      invS[t] = 1.f/(sqrtf(s) + 1e-8f);
    }
    __syncthreads();
    for (int j = t; j < Kn*EMBn; j += 256)
      kn_o[(size_t)blk*Kn*EMBn + j] = kS[j]*invS[j >> 7];
  } else if (blk < 512){
    // ---- wprep ----
    int tid = (blk - 128)*256 + t;
    int k = tid >> 7, n = tid & 127;
    int kt = k >> 5, kr = k & 31, quad = kr >> 3, j = kr & 7;
    int c = n >> 4, ln = n & 15;
    int lane = quad*16 + ln;
    int dst = ((kt*8 + c)*64 + lane)*8 + j;
    Bsw[dst] = f2bf(Wfp[k*128 + n]);
  } else {
    // ---- encmean ----
    int eb = blk - 512;
    int b = eb >> 3, p = eb & 7;
    int d4 = t & 63, rg = t >> 6;
    const float4* e4 = (const float4*)(enc + (size_t)b*Ln*Dn);
    float4 s = make_float4(0.f,0.f,0.f,0.f);
    for (int l = p + 8*rg; l < Ln; l += 32){
      float4 v = e4[(size_t)l*64 + d4];
      s.x += v.x; s.y += v.y; s.z += v.z; s.w += v.w;
    }
    redE[t] = s;
    __syncthreads();
    if (rg == 0){
      float4 o = redE[d4];
      #pragma unroll
      for (int r = 1; r < 4; ++r){
        float4 v = redE[r*64 + d4];
        o.x += v.x; o.y += v.y; o.z += v.z; o.w += v.w;
      }
      ((float4*)(psum + ((size_t)b*8 + p)*Dn))[d4] = o;
    }
  }
}

// ---------- 4. MERGED: gmlp1(1024) | fposm(896); unioned LDS keeps 2 blocks/CU ----------
__global__ __launch_bounds__(256) void k_p4(const float* __restrict__ psum,
    const float* __restrict__ text, const float* __restrict__ vp,
    const float* __restrict__ W1, float* __restrict__ hidp,
    const float* __restrict__ yf, const unsigned short* __restrict__ Bsw,
    const float* __restrict__ bfp, float* __restrict__ fpos, float* __restrict__ finv){
  int blk = blockIdx.x, t = threadIdx.x;
  __shared__ __align__(16) unsigned char smem[FROWS*ASTRIDE*2 + 4*FROWS*4];  // 75264 B
  if (blk < 1024){
    // ---- gmlp1 ----
    float (*inS)[320] = (float(*)[320])smem;
    int bt = blk >> 5, hc = (blk >> 2) & 7, ks = blk & 3;
    for (int j = t; j < 4*320; j += 256){
      int bi = j / 320, jj = j - bi*320;
      int gi = ks*320 + jj;
      int b = bt*4 + bi;
      float vsl;
      if (gi < Dn){
        float s = 0.f;
        for (int p = 0; p < 8; ++p) s += psum[((size_t)b*8 + p)*Dn + gi];
        vsl = s * (1.f/(float)Ln);
      } else if (gi < Dn + TXTn){
        vsl = text[(size_t)b*TXTn + (gi - Dn)];
      } else {
        vsl = vp[gi - Dn - TXTn];
      }
      inS[bi][jj] = vsl;
    }
    __syncthreads();
    int h = t & 63, bi = t >> 6;
    int hidx = hc*64 + h;
    const float* Wb = W1 + (size_t)(ks*320)*512 + hidx;
    float a0 = 0.f, a1 = 0.f, a2 = 0.f, a3 = 0.f;
    const float4* in4 = (const float4*)inS[bi];
    for (int i = 0; i < 320; i += 4){
      float4 x = in4[i >> 2];
      a0 += x.x*Wb[(size_t)(i+0)*512]; a1 += x.y*Wb[(size_t)(i+1)*512];
      a2 += x.z*Wb[(size_t)(i+2)*512]; a3 += x.w*Wb[(size_t)(i+3)*512];
    }
    hidp[((size_t)ks*Bn + bt*4 + bi)*512 + hidx] = (a0 + a1) + (a2 + a3);
  } else {
    // ---- fposm ----
    unsigned short* yS = (unsigned short*)smem;
    float (*rsq)[FROWS] = (float(*)[FROWS])(smem + FROWS*ASTRIDE*2);
    int idx = blk - 1024;
    int b = idx / FTILES, tile = idx % FTILES;
    int h0 = tile*FROWS;
    const float* yb = yf + (size_t)b*Hn*Dn;
    #pragma unroll
    for (int u = 0; u < 12; ++u){
      int unit = t + 256*u;
      int r = unit >> 6, d4 = unit & 63;
      int h = h0 + r;
      int hm1 = h-1 < 0 ? 0 : h-1;
      int hm2 = h-2 < 0 ? 0 : h-2;
      float4 y   = *(const float4*)(yb + (size_t)h  *Dn + d4*4);
      float4 ym1 = *(const float4*)(yb + (size_t)hm1*Dn + d4*4);
      float4 ym2 = *(const float4*)(yb + (size_t)hm2*Dn + d4*4);
      float4 d1 = make_float4(y.x-ym1.x, y.y-ym1.y, y.z-ym1.z, y.w-ym1.w);
      float4 d2 = make_float4(y.x-2.f*ym1.x+ym2.x, y.y-2.f*ym1.y+ym2.y,
                              y.z-2.f*ym1.z+ym2.z, y.w-2.f*ym1.w+ym2.w);
      union { unsigned short u16[4]; uint2 v; } p;
      unsigned short* base = &yS[r*ASTRIDE + d4*4];
      p.u16[0]=f2bf(y.x);  p.u16[1]=f2bf(y.y);  p.u16[2]=f2bf(y.z);  p.u16[3]=f2bf(y.w);
      *(uint2*)(base)        = p.v;
      p.u16[0]=f2bf(d1.x); p.u16[1]=f2bf(d1.y); p.u16[2]=f2bf(d1.z); p.u16[3]=f2bf(d1.w);
      *(uint2*)(base + 256)  = p.v;
      p.u16[0]=f2bf(d2.x); p.u16[1]=f2bf(d2.y); p.u16[2]=f2bf(d2.z); p.u16[3]=f2bf(d2.w);
      *(uint2*)(base + 512)  = p.v;
    }
    __syncthreads();

    int wv   = __builtin_amdgcn_readfirstlane(t >> 6);
    int lane = t & 63, quad = lane >> 4, ln = lane & 15;
    int c0 = wv*2;
    floatx4 acc[3][2];
    #pragma unroll
    for (int i = 0; i < 3; ++i){
      acc[i][0] = (floatx4){0.f,0.f,0.f,0.f};
      acc[i][1] = (floatx4){0.f,0.f,0.f,0.f};
    }
    #pragma unroll
    for (int kt = 0; kt < 24; ++kt){
      int aoff = kt*32 + quad*8;
      short8 a0 = *(const short8*)&yS[( 0 + ln)*ASTRIDE + aoff];
      short8 a1 = *(const short8*)&yS[(16 + ln)*ASTRIDE + aoff];
      short8 a2 = *(const short8*)&yS[(32 + ln)*ASTRIDE + aoff];
      short8 b0 = *(const short8*)&Bsw[((kt*8 + c0  )*64 + lane)*8];
      short8 b1 = *(const short8*)&Bsw[((kt*8 + c0+1)*64 + lane)*8];
      acc[0][0] = __builtin_amdgcn_mfma_f32_16x16x32_bf16(a0, b0, acc[0][0], 0, 0, 0);
      acc[0][1] = __builtin_amdgcn_mfma_f32_16x16x32_bf16(a0, b1, acc[0][1], 0, 0, 0);
      acc[1][0] = __builtin_amdgcn_mfma_f32_16x16x32_bf16(a1, b0, acc[1][0], 0, 0, 0);
      acc[1][1] = __builtin_amdgcn_mfma_f32_16x16x32_bf16(a1, b1, acc[1][1], 0, 0, 0);
      acc[2][0] = __builtin_amdgcn_mfma_f32_16x16x32_bf16(a2, b0, acc[2][0], 0, 0, 0);
      acc[2][1] = __builtin_amdgcn_mfma_f32_16x16x32_bf16(a2, b1, acc[2][1], 0, 0, 0);
    }

    float bias0 = bfp[c0*16 + ln], bias1 = bfp[(c0+1)*16 + ln];
    #pragma unroll
    for (int rt = 0; rt < 3; ++rt){
      #pragma unroll
      for (int reg = 0; reg < 4; ++reg){
        int lrow = rt*16 + quad*4 + reg;
        size_t row = (size_t)b*Hn + h0 + lrow;
        float v0 = acc[rt][0][reg] + bias0;
        float v1 = acc[rt][1][reg] + bias1;
        fpos[row*EMBn + c0*16 + ln]     = v0;
        fpos[row*EMBn + (c0+1)*16 + ln] = v1;
        float sq = v0*v0 + v1*v1;
        sq += __shfl_xor(sq, 1); sq += __shfl_xor(sq, 2);
        sq += __shfl_xor(sq, 4); sq += __shfl_xor(sq, 8);
        if (ln == 0) rsq[wv][lrow] = sq;
      }
    }
    __syncthreads();
    if (t < FROWS){
      float s = rsq[0][t] + rsq[1][t] + rsq[2][t] + rsq[3][t];
      finv[(size_t)b*Hn + h0 + t] = 1.f/(sqrtf(s) + 1e-8f);
    }
  }
}

// ---------- 5. MERGED: gmlp2(256) | cost(512) ----------
__global__ __launch_bounds__(256) void k_p5(const float* __restrict__ hidp,
    const float* __restrict__ b1, const float* __restrict__ W2,
    const float* __restrict__ b2, float* __restrict__ gate_o,
    const float* __restrict__ kn, const float* __restrict__ fpos,
    const float* __restrict__ finv, const float* __restrict__ mu_i,
    float* __restrict__ Km_g){
  int blk = blockIdx.x, t = threadIdx.x;
  __shared__ float hS[4][512];
  __shared__ float pS[8][4][32];
  if (blk < 256){
    // ---- gmlp2 ----
    int bt = blk >> 3, dc = blk & 7;
    for (int j = t; j < 4*512; j += 256){
      int bi = j >> 9, i = j & 511;
      size_t bidx = (size_t)(bt*4 + bi)*512 + i;
      float s = hidp[bidx] + hidp[(size_t)Bn*512 + bidx]
              + hidp[(size_t)2*Bn*512 + bidx] + hidp[(size_t)3*Bn*512 + bidx];
      hS[bi][i] = fmaxf(s + b1[i], 0.f);
    }
    __syncthreads();
    {
      int dl = t & 31, ig = t >> 5;
      int d  = dc*32 + dl;
      float a0=0.f, a1=0.f, a2=0.f, a3=0.f;
      int i0 = ig*64;
      for (int i = i0; i < i0 + 64; ++i){
        float wv = W2[(size_t)i*Dn + d];
        a0 += hS[0][i]*wv; a1 += hS[1][i]*wv;
        a2 += hS[2][i]*wv; a3 += hS[3][i]*wv;
      }
      pS[ig][0][dl] = a0; pS[ig][1][dl] = a1;
      pS[ig][2][dl] = a2; pS[ig][3][dl] = a3;
    }
    __syncthreads();
    if (t < 128){
      int bi = t >> 5, dl = t & 31;
      float s = 0.f;
      #pragma unroll
      for (int g = 0; g < 8; ++g) s += pS[g][bi][dl];
      s += b2[dc*32 + dl];
      gate_o[(size_t)(bt*4 + bi)*Dn + dc*32 + dl] = 1.f/(1.f + expf(-s));
    }
  } else {
    // ---- cost ----
    float* knS = (float*)hS;          // reuse: 16*132 floats = 8448 B < 8192+4096
    float* musS = ((float*)pS) + 0;   // 16 floats
    int cb = blk - 256;
    int b = cb >> 2, q = cb & 3;
    for (int j = t; j < Kn*EMBn; j += 256){
      int k = j >> 7, e = j & 127;
      knS[k*132 + e] = kn[(size_t)b*Kn*EMBn + j];
    }
    if (t < Kn) musS[t] = mu_i[b*Kn + t];
    __syncthreads();
    const int H0 = q*84;
    for (int p = t; p < Kn*84; p += 256){
      int k = p & 15, h = H0 + (p >> 4);
      const float4* f4 = (const float4*)(fpos + ((size_t)b*Hn + h)*EMBn);
      const float4* k4 = (const float4*)(knS + k*132);
      float s = 0.f;
      #pragma unroll 8
      for (int i = 0; i < EMBn/4; ++i){
        float4 a = k4[i], f = f4[i];
        s += a.x*f.x + a.y*f.y + a.z*f.z + a.w*f.w;
      }
      float cs = s*finv[b*Hn + h];
      float th = (h + 0.5f)/(float)Hn;
      float c  = (1.f - cs) + 0.5f*fmaxf(musS[k] - th, 0.f);
      Km_g[(size_t)b*Kn*Hn + k*Hn + h] = expf(-20.f*c);
    }
  }
}

// ---------- 6. Sinkhorn: 2 waves/batch, 3 h-chunks/lane, register butterfly (R6) ----------
__global__ __launch_bounds__(128) void k_sink1w(const float* __restrict__ rr,
    float* KmwT, float* __restrict__ part_cot){
  int b = blockIdx.x, t = threadIdx.x;
  int l = t & 63;
  float* Kb = KmwT + (size_t)b*Kn*Hn;
  int ks = ((l&1)<<3) | ((l&2)<<1) | ((l&4)>>1) | ((l&8)>>3);  // bitrev4(l&15)
  __shared__ float ws[128];
  float km[16][3];
  #pragma unroll
  for (int m = 0; m < 16; ++m){
    const float* rowp = Kb + (size_t)(ks ^ m)*Hn;
    #pragma unroll
    for (int c = 0; c < 3; ++c){
      int h = 128*c + t;
      km[m][c] = (h < Hn) ? rowp[h] : 0.f;
    }
  }
  float rrl = rr[b*Kn + ks];
  float v[3];
  v[0] = 1.f; v[1] = 1.f; v[2] = 1.f;
  float w[16];
  for (int it = 0; it < 30; ++it){
    float p[16];
    #pragma unroll
    for (int m = 0; m < 16; ++m)
      p[m] = km[m][0]*v[0] + km[m][1]*v[1] + km[m][2]*v[2];
    #pragma unroll
    for (int m = 0; m < 8; ++m) p[m] += __shfl_xor(p[m+8], 1);
    #pragma unroll
    for (int m = 0; m < 4; ++m) p[m] += __shfl_xor(p[m+4], 2);
    #pragma unroll
    for (int m = 0; m < 2; ++m) p[m] += __shfl_xor(p[m+2], 4);
    p[0] += __shfl_xor(p[1], 8);
    p[0] += __shfl_xor(p[0], 16);
    p[0] += __shfl_xor(p[0], 32);
    ws[t] = p[0];
    __syncthreads();
    float ptot = ws[l] + ws[64 + l];
    __syncthreads();
    float ul = rrl * rcpf(ptot + 1e-9f);
    w[0] = ul;
    w[1] = __shfl_xor(w[0], 8);
    w[2] = __shfl_xor(w[0], 4); w[3] = __shfl_xor(w[1], 4);
    #pragma unroll
    for (int j = 0; j < 4; ++j) w[4+j] = __shfl_xor(w[j], 2);
    #pragma unroll
    for (int j = 0; j < 8; ++j) w[8+j] = __shfl_xor(w[j], 1);
    #pragma unroll
    for (int c = 0; c < 3; ++c){
      float s0 = 0.f, s1 = 0.f;
      #pragma unroll
      for (int m = 0; m < 8; ++m){ s0 += km[m][c]*w[m]; s1 += km[m+8][c]*w[m+8]; }
      v[c] = (1.f/(float)Hn) * rcpf(s0 + s1 + 1e-9f);
    }
  }
  float q[16];
  #pragma unroll
  for (int m = 0; m < 16; ++m)
    q[m] = km[m][0]*v[0] + km[m][1]*v[1] + km[m][2]*v[2];
  #pragma unroll
  for (int m = 0; m < 8; ++m) q[m] += __shfl_xor(q[m+8], 1);
  #pragma unroll
  for (int m = 0; m < 4; ++m) q[m] += __shfl_xor(q[m+4], 2);
  #pragma unroll
  for (int m = 0; m < 2; ++m) q[m] += __shfl_xor(q[m+2], 4);
  q[0] += __shfl_xor(q[1], 8);
  q[0] += __shfl_xor(q[0], 16);
  q[0] += __shfl_xor(q[0], 32);
  ws[t] = q[0];
  __syncthreads();
  float qtot = ws[l] + ws[64 + l];
  __syncthreads();
  float tt[16];
  tt[0] = qtot;
  tt[1] = __shfl_xor(tt[0], 8);
  tt[2] = __shfl_xor(tt[0], 4); tt[3] = __shfl_xor(tt[1], 4);
  #pragma unroll
  for (int j = 0; j < 4; ++j) tt[4+j] = __shfl_xor(tt[j], 2);
  #pragma unroll
  for (int j = 0; j < 8; ++j) tt[8+j] = __shfl_xor(tt[j], 1);
  float cot = 0.f;
  #pragma unroll
  for (int m = 0; m < 16; ++m){
    float rsinv = rcpf(w[m]*tt[m] + 1e-9f);
    float* rowp = Kb + (size_t)(ks ^ m)*Hn;
    #pragma unroll
    for (int c = 0; c < 3; ++c){
      int h = 128*c + t;
      if (h < Hn){
        float Pi = w[m]*km[m][c]*v[c];
        cot += (-0.05f)*logf(km[m][c])*Pi;   // C = -eps*ln(Km)
        rowp[h] = Pi*rsinv;                  // wT[b][ks^m][h]
      }
    }
  }
  cot = wsum(cot);
  ws[t] = cot;
  __syncthreads();
  if (t == 0) part_cot[b] = ws[0] + ws[64];
}

// ---------- 7. MERGED: mse(1024) | agg(512) ----------
__global__ __launch_bounds__(256) void k_p7(const float* __restrict__ yres,
    const float* __restrict__ yfut, const float* __restrict__ gate,
    const float* __restrict__ ytirs, const float* __restrict__ Wt,
    const float* __restrict__ bt, const float* __restrict__ vp,
    float* __restrict__ part_mse,
    const float* __restrict__ kn, const float* __restrict__ fpos,
    const float* __restrict__ wT, const int* __restrict__ perm,
    float* __restrict__ part_del4){
  int blk = blockIdx.x, t = threadIdx.x;
  __shared__ float redM[256];
  __shared__ float wTl[Hn*4];
  __shared__ float apH[2][4*EMBn];
  __shared__ float a1H[2][4*EMBn];
  __shared__ int permS[EMBn];
  __shared__ float redW[4];
  if (blk < MSEB){
    // ---- mse ----
    const long long total = (long long)Bn*Hn*Dn;
    long long tid = blk*256LL + t;
    const long long nth = (long long)MSEB*256;
    float part = 0.f;
    for (long long i4 = tid; i4*4 < total; i4 += nth){
      long long base = i4*4;
      int b = (int)(base/((long long)Hn*Dn));
      int rem = (int)(base - (long long)b*Hn*Dn);
      int h = rem/Dn, d = rem - h*Dn;
      float4 yr = *(const float4*)(yres + base);
      float4 yv = *(const float4*)(yfut + base);
      float4 g  = *(const float4*)(gate + (size_t)b*Dn + d);
      float4 wt = *(const float4*)(Wt + d);
      float4 bv = *(const float4*)(bt + d);
      float4 vv = *(const float4*)(vp + d);
      float ys = ytirs[b*Hn + h];
      float yt, yh, e;
      yt = (ys*wt.x + bv.x)*vv.x; yh = yr.x + 0.5f*g.x*(yt-yr.x); e = yh-yv.x; part += e*e;
      yt = (ys*wt.y + bv.y)*vv.y; yh = yr.y + 0.5f*g.y*(yt-yr.y); e = yh-yv.y; part += e*e;
      yt = (ys*wt.z + bv.z)*vv.z; yh = yr.z + 0.5f*g.z*(yt-yr.z); e = yh-yv.z; part += e*e;
      yt = (ys*wt.w + bv.w)*vv.w; yh = yr.w + 0.5f*g.w*(yt-yr.w); e = yh-yv.w; part += e*e;
    }
    redM[t] = part; __syncthreads();
    for (int s = 128; s > 0; s >>= 1){
      if (t < s) redM[t] += redM[t + s];
      __syncthreads();
    }
    if (t == 0) part_mse[blk] = redM[0];
  } else {
    // ---- agg ----
    int ab = blk - MSEB;
    int b = ab >> 2, kg = ab & 3;
    if (t < EMBn) permS[t] = perm[t];
    for (int j = t; j < 4*Hn; j += 256){
      int k = j & 3, h = j >> 2;
      wTl[h*4 + k] = wT[(size_t)b*Kn*Hn + (size_t)(kg*4 + k)*Hn + h];
    }
    __syncthreads();
    {
      int e = t & 127, jh = t >> 7;
      float ap[4], a1[4];
      #pragma unroll
      for (int j = 0; j < 4; ++j){ ap[j] = 0.f; a1[j] = 0.f; }
      const float* fb = fpos + (size_t)b*Hn*EMBn + e;
      int hh0 = jh*168, hh1 = hh0 + 168;
      for (int h = hh0; h < hh1; ++h){
        float fv = fb[(size_t)h*EMBn];
        int h1 = h + SHIFT; if (h1 >= Hn) h1 -= Hn;
        float4 wA = *(const float4*)&wTl[h *4];
        float4 wB = *(const float4*)&wTl[h1*4];
        ap[0] += wA.x*fv; ap[1] += wA.y*fv; ap[2] += wA.z*fv; ap[3] += wA.w*fv;
        a1[0] += wB.x*fv; a1[1] += wB.y*fv; a1[2] += wB.z*fv; a1[3] += wB.w*fv;
      }
      #pragma unroll
      for (int j = 0; j < 4; ++j){
        apH[jh][j*EMBn + e] = ap[j];
        a1H[jh][j*EMBn + e] = a1[j];
      }
    }
    __syncthreads();
    for (int j = t; j < 4*EMBn; j += 256){
      apH[0][j] += apH[1][j];
      a1H[0][j] += a1H[1][j];
    }
    __syncthreads();
    int wave = t >> 6, lane = t & 63;
    {
      int kl = wave;
      int k  = kg*4 + kl;
      float sp = 0.f, s1 = 0.f, s2 = 0.f, np = 0.f, n1 = 0.f;
      for (int e = lane; e < EMBn; e += 64){
        float kne = kn[((size_t)b*Kn + k)*EMBn + e];
        float a  = apH[0][kl*EMBn + e];
        float c1 = a1H[0][kl*EMBn + e];
        sp += kne*a; s1 += kne*c1;
        s2 += kne*apH[0][kl*EMBn + permS[e]];
        np += a*a; n1 += c1*c1;
      }
      for (int o = 32; o; o >>= 1){
        sp += __shfl_down(sp, o); s1 += __shfl_down(s1, o); s2 += __shfl_down(s2, o);
        np += __shfl_down(np, o); n1 += __shfl_down(n1, o);
      }
      if (lane == 0){
        float ip  = 1.f/(sqrtf(np) + 1e-8f);
        float i1v = 1.f/(sqrtf(n1) + 1e-8f);
        const float ti = 1.f/0.07f;
        float l0 = sp*ip*ti, l1 = s1*i1v*ti, l2 = s2*ip*ti;
        float m = fmaxf(l0, fmaxf(l1, l2));
        float lse = m + logf(expf(l0-m) + expf(l1-m) + expf(l2-m));
        redW[wave] = lse - l0;
      }
    }
    __syncthreads();
    if (t == 0) part_del4[(size_t)b*4 + kg] = redW[0] + redW[1] + redW[2] + redW[3];
  }
}

// ---------- 8. combine ----------
__global__ void k_final(const float* __restrict__ part_mse, const float* __restrict__ part_cot,
                        const float* __restrict__ part_del4, const float* __restrict__ part_ent,
                        const float* __restrict__ part_tv, float* __restrict__ out){
  int t = threadIdx.x;  // 256
  __shared__ double sred[256];
  double m = 0.0;
  for (int i = t; i < MSEB; i += 256) m += (double)part_mse[i];
  double o4 = 0.0;
  if (t < Bn){
    double del = (double)part_del4[4*t] + (double)part_del4[4*t + 1]
               + (double)part_del4[4*t + 2] + (double)part_del4[4*t + 3];
    o4 = 0.1*(double)part_cot[t] + (0.1/(double)Kn)*del
       - (0.01/(double)Kn)*(double)part_ent[t] + (0.01/(double)(Kn-1))*(double)part_tv[t];
  }
  sred[t] = m/((double)Bn*Hn*Dn) + o4/(double)Bn;
  __syncthreads();
  for (int s = 128; s > 0; s >>= 1){ if (t < s) sred[t] += sred[t+s]; __syncthreads(); }
  if (t == 0) out[0] = (float)sred[0];
}

// ---------- launch ----------
extern "C" void kernel_launch(void* const* d_in, const int* in_sizes, int n_in,
                              void* d_out, int out_size, void* d_ws, size_t ws_size,
                              hipStream_t stream) {
  const float* y_res  = (const float*)d_in[0];
  const float* text   = (const float*)d_in[1];
  const float* enc    = (const float*)d_in[2];
  const float* yfut   = (const float*)d_in[3];
  const int*   perm   = (const int*)  d_in[4];
  const float* W_t2k  = (const float*)d_in[5];
  const float* b_t2k  = (const float*)d_in[6];
  const float* W_kemb = (const float*)d_in[7];
  const float* b_kemb = (const float*)d_in[8];
  const float* W_tir  = (const float*)d_in[9];
  const float* b_tir  = (const float*)d_in[10];
  const float* vproj  = (const float*)d_in[11];
  const float* W_g1   = (const float*)d_in[12];
  const float* b_g1   = (const float*)d_in[13];
  const float* W_g2   = (const float*)d_in[14];
  const float* b_g2   = (const float*)d_in[15];
  const float* W_fp   = (const float*)d_in[16];
  const float* b_fp   = (const float*)d_in[17];

  float* F = (float*)d_ws;
  float* mu_w   = F;            // 2048
  float* rr_w   = F + 2048;     // 2048
  float* ytr_w  = F + 4096;     // 43008
  float* kapT_w = F + 47104;    // 688128  (lifecycle: kapT -> Bsw -> Km -> wT)
  float* kn_w   = F + 735232;   // 262144
  float* gate_w = F + 997376;   // 32768
  float* fp_w   = F + 1030144;  // 5505024 (kp overlay dies before fposm writes)
  float* fi_w   = F + 6535168;  // 43008
  float* pmse_w = F + 6578176;  // 1024
  float* pcot_w = F + 6579200;  // 128
  float* pent_w = F + 6579456;  // 128
  float* ptv_w  = F + 6579584;  // 128
  // fresh regions (no overlay: these are live concurrently with fp_w/gate_w users)
  float* psum_w  = F + 6579712; // 262144 -> ends 6841856
  float* hidp_w  = F + 6841856; // 262144 -> ends 7104000
  float* pdel4_w = F + 7104000; // 512    -> ends 7104512 (28.4 MB total)
  unsigned short* Bsw_w = (unsigned short*)kapT_w;  // 192 KB, dead after k_p4
  float* KmwT_w = kapT_w;                            // 2.75 MB, exact-size overlay
  float* kp_w   = fp_w;                              // kemb1 partials, dead after k_p3

  k_fused1 <<<Bn, 256, 0, stream>>>(text, W_t2k, b_t2k, mu_w, kapT_w, rr_w, ytr_w, pent_w, ptv_w);
  k_kemb1  <<<Bn*8, 128, 0, stream>>>(kapT_w, W_kemb, kp_w);
  k_p3     <<<1536, 256, 0, stream>>>(kp_w, b_kemb, kn_w, W_fp, Bsw_w, enc, psum_w);
  k_p4     <<<1920, 256, 0, stream>>>(psum_w, text, vproj, W_g1, hidp_w,
                                      yfut, Bsw_w, b_fp, fp_w, fi_w);
  k_p5     <<<768, 256, 0, stream>>>(hidp_w, b_g1, W_g2, b_g2, gate_w,
                                     kn_w, fp_w, fi_w, mu_w, KmwT_w);
  k_sink1w <<<Bn, 128, 0, stream>>>(rr_w, KmwT_w, pcot_w);
  k_p7     <<<1536, 256, 0, stream>>>(y_res, yfut, gate_w, ytr_w, W_tir, b_tir, vproj,
                                      pmse_w, kn_w, fp_w, KmwT_w, perm, pdel4_w);
  k_final  <<<1, 256, 0, stream>>>(pmse_w, pcot_w, pdel4_w, pent_w, ptv_w, (float*)d_out);
}